// Round 1
// baseline (1997.523 us; speedup 1.0000x reference)
//
#include <hip/hip_runtime.h>
#include <hip/hip_bf16.h>

// Problem: G is (B=8192, P=2048) fp32. F = G^T G / B (P x P).
// Output: 0.1 * relu(1 - lambda_min(F)) as a single fp32.
// Strategy: fp32 tiled GEMM to form F in workspace, 64-step Lanczos for
// lambda_min, Sturm-sequence bisection on the tridiagonal in a 1-thread kernel.

#define PDIM 2048
#define BDIM 8192
#define LM 64           // Lanczos iterations

// ---------------- GEMM: F = G^T G / B ----------------
// 64x64 tile, BK=16, 256 threads, 4x4 microtile per thread.
#define BM 64
#define BN 64
#define BK 16

__global__ __launch_bounds__(256) void fisher_gemm(const float* __restrict__ G,
                                                   float* __restrict__ F) {
    __shared__ float As[BK][BM];
    __shared__ float Bs[BK][BN];
    const int i0 = blockIdx.y * BM;
    const int j0 = blockIdx.x * BN;
    const int tid = threadIdx.x;
    const int tr = tid >> 4;        // 0..15
    const int tc = tid & 15;        // 0..15
    const int lrow = tid >> 4;      // loader row within BK (0..15)
    const int lcol = (tid & 15) * 4;// loader col (0..60)

    float acc[4][4] = {};

    for (int k0 = 0; k0 < BDIM; k0 += BK) {
        const float* gA = G + (size_t)(k0 + lrow) * PDIM + i0 + lcol;
        const float* gB = G + (size_t)(k0 + lrow) * PDIM + j0 + lcol;
        float4 a4 = *(const float4*)gA;
        float4 b4 = *(const float4*)gB;
        __syncthreads();
        *(float4*)&As[lrow][lcol] = a4;
        *(float4*)&Bs[lrow][lcol] = b4;
        __syncthreads();
#pragma unroll
        for (int kk = 0; kk < BK; ++kk) {
            float4 av = *(const float4*)&As[kk][tr * 4];
            float4 bv = *(const float4*)&Bs[kk][tc * 4];
            float a[4] = {av.x, av.y, av.z, av.w};
            float b[4] = {bv.x, bv.y, bv.z, bv.w};
#pragma unroll
            for (int x = 0; x < 4; ++x)
#pragma unroll
                for (int y = 0; y < 4; ++y)
                    acc[x][y] += a[x] * b[y];
        }
    }
    const float scale = 1.0f / (float)BDIM;
#pragma unroll
    for (int x = 0; x < 4; ++x)
#pragma unroll
        for (int y = 0; y < 4; ++y)
            F[(size_t)(i0 + tr * 4 + x) * PDIM + (j0 + tc * 4 + y)] = acc[x][y] * scale;
}

// ---------------- Lanczos ----------------
__device__ __forceinline__ float hash_to_float(unsigned x) {
    x = (x ^ 61u) ^ (x >> 16);
    x *= 9u;
    x ^= x >> 4;
    x *= 0x27d4eb2du;
    x ^= x >> 15;
    return (float)(x & 0xFFFFFFu) / 16777216.0f - 0.5f;
}

// S[k] holds s_{k-1} = ||u_{k-1}||^2  (S[0] = s_{-1} = 1 sentinel)
// D[j] holds u_j . (F u_j)
__global__ void lanczos_init(float* __restrict__ uA, float* __restrict__ uB,
                             float* __restrict__ S, float* __restrict__ D) {
    const int tid = threadIdx.x; // 256 threads, 1 block
    if (tid < LM + 2) S[tid] = (tid == 0) ? 1.0f : 0.0f;
    if (tid < LM) D[tid] = 0.0f;
    float local = 0.0f;
    for (int i = tid; i < PDIM; i += 256) {
        uB[i] = 0.0f;
        float v = hash_to_float((unsigned)i * 2654435761u + 12345u);
        uA[i] = v;
        local += v * v;
    }
    for (int off = 32; off; off >>= 1) local += __shfl_down(local, off, 64);
    __shared__ float red[4];
    if ((tid & 63) == 0) red[tid >> 6] = local;
    __syncthreads();
    if (tid == 0) S[1] = red[0] + red[1] + red[2] + red[3];
}

// t = F * u ; atomic accumulate d += u.t   (grid: 512 blocks x 256 thr, 1 wave/row)
__global__ __launch_bounds__(256) void lanczos_mv(const float* __restrict__ F,
                                                  const float* __restrict__ u,
                                                  float* __restrict__ t,
                                                  float* d_accum) {
    const int row = blockIdx.x * 4 + (threadIdx.x >> 6);
    const int lane = threadIdx.x & 63;
    const float* Frow = F + (size_t)row * PDIM;
    float sum = 0.0f;
    for (int c = lane * 4; c < PDIM; c += 256) {
        float4 f4 = *(const float4*)&Frow[c];
        float4 u4 = *(const float4*)&u[c];
        sum += f4.x * u4.x + f4.y * u4.y + f4.z * u4.z + f4.w * u4.w;
    }
    for (int off = 32; off; off >>= 1) sum += __shfl_down(sum, off, 64);
    __shared__ float red[4];
    if (lane == 0) {
        t[row] = sum;
        red[threadIdx.x >> 6] = sum * u[row];
    }
    __syncthreads();
    if (threadIdx.x == 0) atomicAdd(d_accum, red[0] + red[1] + red[2] + red[3]);
}

// u_{j+1} = t/n_j - (alpha_j/n_j) u_j - (n_j/n_{j-1}) u_{j-1}; accumulate ||u_{j+1}||^2
// upn: holds u_{j-1} on entry, u_{j+1} on exit. (grid: 8 blocks x 256 thr)
__global__ void lanczos_upd(const float* __restrict__ t, const float* __restrict__ u,
                            float* __restrict__ upn,
                            const float* pSj, const float* pSjm1,
                            const float* pDj, float* pSjp1) {
    const float s_j = *pSj;
    const float s_jm1 = *pSjm1;
    const float d_j = *pDj;
    const float n_j = sqrtf(s_j);
    const float inv_n = 1.0f / n_j;
    const float alpha = d_j / s_j;
    const float c_u = alpha * inv_n;
    const float c_p = n_j / sqrtf(s_jm1);
    const int i = blockIdx.x * blockDim.x + threadIdx.x;
    const float un = t[i] * inv_n - c_u * u[i] - c_p * upn[i];
    upn[i] = un;
    float sq = un * un;
    for (int off = 32; off; off >>= 1) sq += __shfl_down(sq, off, 64);
    __shared__ float red[4];
    if ((threadIdx.x & 63) == 0) red[threadIdx.x >> 6] = sq;
    __syncthreads();
    if (threadIdx.x == 0) atomicAdd(pSjp1, red[0] + red[1] + red[2] + red[3]);
}

// Smallest eigenvalue of the tridiagonal via Sturm bisection, then the penalty.
__global__ void lanczos_final(const float* __restrict__ S, const float* __restrict__ D,
                              float* __restrict__ out) {
    double diag[LM], off[LM - 1];
    for (int j = 0; j < LM; ++j) diag[j] = (double)D[j] / (double)S[j + 1];
    for (int j = 0; j < LM - 1; ++j) off[j] = sqrt((double)S[j + 2]);

    double lo = 1e300, hi = 1e300;
    for (int j = 0; j < LM; ++j) {
        double r = diag[j];
        if (j > 0) r -= fabs(off[j - 1]);
        if (j < LM - 1) r -= fabs(off[j]);
        lo = fmin(lo, r);
        hi = fmin(hi, diag[j]);
    }
    lo -= 1e-3;
    hi += 1e-3;

    for (int it = 0; it < 200 && (hi - lo) > 1e-10; ++it) {
        double x = 0.5 * (lo + hi);
        int cnt = 0;
        double q = 1.0;
        for (int j = 0; j < LM; ++j) {
            double b2 = (j > 0) ? off[j - 1] * off[j - 1] : 0.0;
            q = diag[j] - x - b2 / q;
            if (q < 0.0) cnt++;
            if (fabs(q) < 1e-300) q = -1e-300;
        }
        if (cnt >= 1) hi = x; else lo = x;
    }
    double lam = 0.5 * (lo + hi);
    double pen = 1.0 - lam;
    if (pen < 0.0) pen = 0.0;
    out[0] = (float)(0.1 * pen);
}

// ---------------- launch ----------------
extern "C" void kernel_launch(void* const* d_in, const int* in_sizes, int n_in,
                              void* d_out, int out_size, void* d_ws, size_t ws_size,
                              hipStream_t stream) {
    const float* G = (const float*)d_in[0];

    float* F  = (float*)d_ws;                       // 2048*2048 fp32 = 16.8 MB
    float* uA = F + (size_t)PDIM * PDIM;            // 2048
    float* uB = uA + PDIM;                          // 2048
    float* t  = uB + PDIM;                          // 2048
    float* S  = t + PDIM;                           // LM+2
    float* D  = S + (LM + 2);                       // LM

    fisher_gemm<<<dim3(PDIM / BN, PDIM / BM), 256, 0, stream>>>(G, F);
    lanczos_init<<<1, 256, 0, stream>>>(uA, uB, S, D);

    float* uc = uA;  // u_j
    float* up = uB;  // u_{j-1} (becomes u_{j+1})
    for (int j = 0; j < LM; ++j) {
        lanczos_mv<<<PDIM / 4, 256, 0, stream>>>(F, uc, t, &D[j]);
        lanczos_upd<<<PDIM / 256, 256, 0, stream>>>(t, uc, up, &S[j + 1], &S[j], &D[j], &S[j + 2]);
        float* tmp = up; up = uc; uc = tmp;
    }
    lanczos_final<<<1, 1, 0, stream>>>(S, D, (float*)d_out);
}